// Round 6
// baseline (295.249 us; speedup 1.0000x reference)
//
#include <hip/hip_runtime.h>
#include <math.h>

#define PI9 (2.0f * 3.14159265358979323846f / 9.0f)

typedef float f32x4 __attribute__((ext_vector_type(4)));
typedef unsigned short us8 __attribute__((ext_vector_type(8)));
typedef __bf16 bf16x8 __attribute__((ext_vector_type(8)));

__device__ __forceinline__ float ssp_f(float x) {
  const float ax = fabsf(x);
  const float t = __expf(-ax);
  return fmaxf(x, 0.f) + __logf(1.f + t) - 0.69314718f;
}

__device__ __forceinline__ unsigned short f2bf(float f) {
  unsigned int u = __float_as_uint(f);
  unsigned int r = (u + 0x7FFFu + ((u >> 16) & 1u)) >> 16;
  return (unsigned short)r;
}

// ===========================================================================
// prep_kernel: blocks [0,nMlp) = MLP, [nMlp,nMlp+nScat) = scatter,
//              [nMlp+nScat, +9) = precompute_C.   Shared-memory union 32 KB.
// ===========================================================================
__device__ void mlp_body(
    int mblk, unsigned char* smem, const float* __restrict__ win,
    const float* __restrict__ W1, const float* __restrict__ W2,
    const float* __restrict__ W3, const float* __restrict__ a_w,
    const float* __restrict__ den, float* __restrict__ w48) {
  float* W1s = (float*)smem;                              // 2048 B
  unsigned short* W2T = (unsigned short*)(smem + 2048);   // 8192 B
  unsigned short* W3T = (unsigned short*)(smem + 10240);  // 6144 B
  unsigned short* H1 = (unsigned short*)(smem + 16384);   // 8192 B
  unsigned short* H2 = (unsigned short*)(smem + 24576);   // 8192 B
  const int t = threadIdx.x;

  const float invden = 1.f / den[0];
  const float sc0 = a_w[0] * invden, sc1 = a_w[10] * invden, sc2 = a_w[22] * invden;
  const float rs8 = 0.35355339059327373f;

  if (t < 128) {
    float4 v = ((const float4*)W1)[t];
    v.x *= rs8; v.y *= rs8; v.z *= rs8; v.w *= rs8;
    ((float4*)W1s)[t] = v;
  }
  for (int i = t; i < 4096; i += 256) {
    const int k = i >> 6, j = i & 63;
    W2T[j * 64 + ((((k >> 3) ^ (j & 7)) << 3)) + (k & 7)] = f2bf(W2[i] * 0.125f);
  }
  for (int i = t; i < 3072; i += 256) {
    const int k = i / 48, j = i % 48;
    const int jm = j % 3;
    const float s = (jm == 0) ? sc0 : ((jm == 1) ? sc1 : sc2);
    W3T[j * 64 + ((((k >> 3) ^ (j & 7)) << 3)) + (k & 7)] = f2bf(W3[i] * 0.125f * s);
  }
  __syncthreads();

  const int w = t >> 6, l = t & 63;
  const int er = l & 15, g = l >> 4;
  unsigned short* h1p = H1 + w * 1024;
  unsigned short* h2p = H2 + w * 1024;

#pragma unroll 1
  for (int rep = 0; rep < 2; ++rep) {
    const int e = mblk * 128 + rep * 64 + w * 16 + er;

    float in8[8];
    {
      const float4 A = *(const float4*)(win + (size_t)e * 8);
      const float4 B = *(const float4*)(win + (size_t)e * 8 + 4);
      in8[0] = A.x; in8[1] = A.y; in8[2] = A.z; in8[3] = A.w;
      in8[4] = B.x; in8[5] = B.y; in8[6] = B.z; in8[7] = B.w;
    }
    float h[16];
#pragma unroll
    for (int c = 0; c < 16; ++c) h[c] = 0.f;
#pragma unroll
    for (int k = 0; k < 8; ++k) {
      const float* wr = &W1s[k * 64 + g * 16];
      const float4 w0 = *(const float4*)wr;
      const float4 w1 = *(const float4*)(wr + 4);
      const float4 w2 = *(const float4*)(wr + 8);
      const float4 w3 = *(const float4*)(wr + 12);
      const float ik = in8[k];
      h[0]  = fmaf(ik, w0.x, h[0]);  h[1]  = fmaf(ik, w0.y, h[1]);
      h[2]  = fmaf(ik, w0.z, h[2]);  h[3]  = fmaf(ik, w0.w, h[3]);
      h[4]  = fmaf(ik, w1.x, h[4]);  h[5]  = fmaf(ik, w1.y, h[5]);
      h[6]  = fmaf(ik, w1.z, h[6]);  h[7]  = fmaf(ik, w1.w, h[7]);
      h[8]  = fmaf(ik, w2.x, h[8]);  h[9]  = fmaf(ik, w2.y, h[9]);
      h[10] = fmaf(ik, w2.z, h[10]); h[11] = fmaf(ik, w2.w, h[11]);
      h[12] = fmaf(ik, w3.x, h[12]); h[13] = fmaf(ik, w3.y, h[13]);
      h[14] = fmaf(ik, w3.z, h[14]); h[15] = fmaf(ik, w3.w, h[15]);
    }
    us8 pk0, pk1;
#pragma unroll
    for (int jj = 0; jj < 8; ++jj) pk0[jj] = f2bf(ssp_f(h[jj]));
#pragma unroll
    for (int jj = 0; jj < 8; ++jj) pk1[jj] = f2bf(ssp_f(h[8 + jj]));
    *(us8*)&h1p[er * 64 + (((2 * g) ^ (er & 7)) << 3)] = pk0;
    *(us8*)&h1p[er * 64 + (((2 * g + 1) ^ (er & 7)) << 3)] = pk1;
    __builtin_amdgcn_wave_barrier();

    const us8 a0 = *(const us8*)&h1p[er * 64 + ((g ^ (er & 7)) << 3)];
    const us8 a1 = *(const us8*)&h1p[er * 64 + (((g + 4) ^ (er & 7)) << 3)];
    float hh[16];
#pragma unroll
    for (int nt = 0; nt < 4; ++nt) {
      const int j = nt * 16 + er;
      const us8 b0 = *(const us8*)&W2T[j * 64 + ((g ^ (j & 7)) << 3)];
      const us8 b1 = *(const us8*)&W2T[j * 64 + (((g + 4) ^ (j & 7)) << 3)];
      f32x4 acc = {0.f, 0.f, 0.f, 0.f};
      acc = __builtin_amdgcn_mfma_f32_16x16x32_bf16(
          __builtin_bit_cast(bf16x8, a0), __builtin_bit_cast(bf16x8, b0), acc, 0, 0, 0);
      acc = __builtin_amdgcn_mfma_f32_16x16x32_bf16(
          __builtin_bit_cast(bf16x8, a1), __builtin_bit_cast(bf16x8, b1), acc, 0, 0, 0);
#pragma unroll
      for (int r = 0; r < 4; ++r) hh[nt * 4 + r] = ssp_f(acc[r]);
    }
#pragma unroll
    for (int nt = 0; nt < 4; ++nt)
#pragma unroll
      for (int r = 0; r < 4; ++r) {
        const int e2 = g * 4 + r;
        const int k2 = nt * 16 + er;
        h2p[e2 * 64 + ((((k2 >> 3) ^ (e2 & 7)) << 3)) + (k2 & 7)] = f2bf(hh[nt * 4 + r]);
      }
    __builtin_amdgcn_wave_barrier();

    const us8 c0 = *(const us8*)&h2p[er * 64 + ((g ^ (er & 7)) << 3)];
    const us8 c1 = *(const us8*)&h2p[er * 64 + (((g + 4) ^ (er & 7)) << 3)];
    const int ebase = mblk * 128 + rep * 64 + w * 16 + g * 4;
#pragma unroll
    for (int nt = 0; nt < 3; ++nt) {
      const int o = nt * 16 + er;
      const us8 b0 = *(const us8*)&W3T[o * 64 + ((g ^ (o & 7)) << 3)];
      const us8 b1 = *(const us8*)&W3T[o * 64 + (((g + 4) ^ (o & 7)) << 3)];
      f32x4 acc = {0.f, 0.f, 0.f, 0.f};
      acc = __builtin_amdgcn_mfma_f32_16x16x32_bf16(
          __builtin_bit_cast(bf16x8, c0), __builtin_bit_cast(bf16x8, b0), acc, 0, 0, 0);
      acc = __builtin_amdgcn_mfma_f32_16x16x32_bf16(
          __builtin_bit_cast(bf16x8, c1), __builtin_bit_cast(bf16x8, b1), acc, 0, 0, 0);
#pragma unroll
      for (int r = 0; r < 4; ++r)
        w48[(size_t)(ebase + r) * 48 + o] = acc[r];
    }
    __builtin_amdgcn_wave_barrier();
  }
}

__device__ void precompute_body(
    int d, unsigned char* smem,
    const float* __restrict__ Ux_re, const float* __restrict__ Ux_im,
    const float* __restrict__ Uf_re, const float* __restrict__ Uf_im,
    const float* __restrict__ Vo_re, const float* __restrict__ Vo_im,
    float* __restrict__ CT) {
  float* G = (float*)smem;                // 2*729 floats = 5832 B
  float* TL = (float*)(smem + 5840);      // 2916 B
  float* cs9 = (float*)(smem + 8768);
  float* sn9 = (float*)(smem + 8816);
  const int t0 = threadIdx.x;

  if (t0 < 9) {
    float s, c;
    __sincosf(PI9 * (float)t0, &s, &c);
    cs9[t0] = c; sn9[t0] = s;
  }
  __syncthreads();

  for (int t = t0; t < 1458; t += 256) {
    const int which = t / 729, idx = t % 729;
    const int p = idx / 81, ab = idx % 81, a = ab / 9, b = ab % 9;
    const float* Ure = which ? Uf_re : Ux_re;
    const float* Uim = which ? Uf_im : Ux_im;
    float g = 0.f;
#pragma unroll
    for (int v = 0; v < 3; ++v) {
      const int uc = v + 2;
      float hre = 0.f, him = 0.f;
#pragma unroll
      for (int ui = 0; ui < 5; ++ui) {
        const int u = (ui + 7) % 9;
        const float re = Ure[p * 25 + ui * 5 + uc];
        const float im = Uim[p * 25 + ui * 5 + uc];
        const int k = (u * a) % 9;
        const float c = cs9[k], s = sn9[k];
        hre += re * c - im * s;
        him += re * s + im * c;
      }
      hre *= (1.f / 9.f); him *= (1.f / 9.f);
      if (v == 0) {
        g += hre;
      } else {
        const int k = (v * b) % 9;
        g += 2.f * (hre * cs9[k] - him * sn9[k]);
      }
    }
    G[which * 729 + p * 81 + ab] = g * (1.f / 9.f);
  }
  __syncthreads();

  for (int t = t0; t < 729; t += 256) {
    const int ab = t / 9, dd = t % 9, a = ab / 9, b = ab % 9;
    float acc = 0.f;
    for (int u = 0; u < 9; ++u)
      for (int v = 0; v < 5; ++v) {
        const int k = (u * a + v * b) % 9;
        acc += Vo_re[u * 45 + v * 9 + dd] * cs9[k]
             + Vo_im[u * 45 + v * 9 + dd] * sn9[k];
      }
    TL[ab * 9 + dd] = acc;
  }
  __syncthreads();

  if (t0 < 108) {
    const int p = t0 / 12, q = t0 % 12;
    float acc = 0.f;
    if (q < 9) {
      for (int ab = 0; ab < 81; ++ab)
        acc += G[p * 81 + ab] * G[729 + q * 81 + ab] * TL[ab * 9 + d];
    }
    CT[(d * 9 + p) * 12 + q] = acc;
  }
}

__global__ __launch_bounds__(256) void prep_kernel(
    const float* __restrict__ win, const float* __restrict__ W1,
    const float* __restrict__ W2, const float* __restrict__ W3,
    const float* __restrict__ a_w, const float* __restrict__ den,
    float* __restrict__ w48,
    const int* __restrict__ dst, const int* __restrict__ src, int E,
    int* __restrict__ cnt, int2* __restrict__ slots2,
    const float* __restrict__ Ux_re, const float* __restrict__ Ux_im,
    const float* __restrict__ Uf_re, const float* __restrict__ Uf_im,
    const float* __restrict__ Vo_re, const float* __restrict__ Vo_im,
    float* __restrict__ CT, int nMlp, int nScat) {
  __shared__ __align__(16) unsigned char smem[32768];
  const int bid = blockIdx.x;
  if (bid < nMlp) {
    mlp_body(bid, smem, win, W1, W2, W3, a_w, den, w48);
  } else if (bid < nMlp + nScat) {
    const int e = (bid - nMlp) * 256 + threadIdx.x;
    if (e < E) {
      const int d = dst[e];
      const int pos = atomicAdd(&cnt[d], 1);
      if (pos < 96) slots2[(size_t)d * 96 + pos] = make_int2(e, src[e]);
    }
  } else {
    precompute_body(bid - nMlp - nScat, smem, Ux_re, Ux_im, Uf_re, Uf_im,
                    Vo_re, Vo_im, CT);
  }
}

// ===========================================================================
// Node kernel v5: 8 waves/node (512 thr), 3-stage rotating prefetch pipeline,
// packed (e,src) slots, C rows in VGPRs, padded LDS.
// ===========================================================================
#define NLOAD(S, idx)                                                        \
  {                                                                          \
    const int ix_ = (idx);                                                   \
    if (ix_ < deg) {                                                         \
      const int2 es_ = sl2[ix_];                                             \
      const int e_ = __builtin_amdgcn_readfirstlane(es_.x);                  \
      const int s_ = __builtin_amdgcn_readfirstlane(es_.y);                  \
      _Pragma("unroll")                                                      \
      for (int q_ = 0; q_ < 9; ++q_) S##f[q_] = filt[(size_t)e_ * 9 + q_];   \
      if (l < 36) S##x = *(const float4*)(x + (size_t)s_ * 144 + l * 4);     \
      else S##x = make_float4(0.f, 0.f, 0.f, 0.f);                           \
      S##w0 = w48[(size_t)e_ * 48 + wc0];                                    \
      S##w12 = w48[(size_t)e_ * 48 + wc12];                                  \
    } else {                                                                 \
      _Pragma("unroll")                                                      \
      for (int q_ = 0; q_ < 9; ++q_) S##f[q_] = 0.f;                         \
      S##x = make_float4(0.f, 0.f, 0.f, 0.f);                                \
      S##w0 = 0.f; S##w12 = 0.f;                                             \
    }                                                                        \
  }

#define NCOMPUTE(S)                                                          \
  {                                                                          \
    if (l < 36) {                                                            \
      xsl[w][wa0] = S##x.x; xsl[w][wa1] = S##x.y;                            \
      xsl[w][wa2] = S##x.z; xsl[w][wa3] = S##x.w;                            \
    }                                                                        \
    {                                                                        \
      float me = S##f[0] * C0a.x;                                            \
      me = fmaf(S##f[1], C0a.y, me); me = fmaf(S##f[2], C0a.z, me);          \
      me = fmaf(S##f[3], C0a.w, me); me = fmaf(S##f[4], C0b.x, me);          \
      me = fmaf(S##f[5], C0b.y, me); me = fmaf(S##f[6], C0b.z, me);          \
      me = fmaf(S##f[7], C0b.w, me); me = fmaf(S##f[8], C0c, me);            \
      MeT[w][me0] = me;                                                      \
    }                                                                        \
    if (l < 17) {                                                            \
      float me = S##f[0] * C1a.x;                                            \
      me = fmaf(S##f[1], C1a.y, me); me = fmaf(S##f[2], C1a.z, me);          \
      me = fmaf(S##f[3], C1a.w, me); me = fmaf(S##f[4], C1b.x, me);          \
      me = fmaf(S##f[5], C1b.y, me); me = fmaf(S##f[6], C1b.z, me);          \
      me = fmaf(S##f[7], C1b.w, me); me = fmaf(S##f[8], C1c, me);            \
      MeT[w][me1] = me;                                                      \
    }                                                                        \
    __builtin_amdgcn_wave_barrier();                                         \
    {                                                                        \
      const float* xr = &xsl[w][m * 12];                                     \
      const float4 x0 = *(const float4*)xr;                                  \
      const float4 x1 = *(const float4*)(xr + 4);                            \
      const float x8 = xr[8];                                                \
      const float* mr0 = &MeT[w][K * 12];                                    \
      const float4 ma = *(const float4*)mr0;                                 \
      const float4 mb = *(const float4*)(mr0 + 4);                           \
      float v = x0.x * ma.x + x0.y * ma.y + x0.z * ma.z + x0.w * ma.w        \
              + x1.x * mb.x + x1.y * mb.y + x1.z * mb.z + x1.w * mb.w        \
              + x8 * mr0[8];                                                 \
      a0 = fmaf(v, S##w0, a0);                                               \
      const float* mr1 = &MeT[w][(K + 4) * 12];                              \
      const float4 mc = *(const float4*)mr1;                                 \
      const float4 md = *(const float4*)(mr1 + 4);                           \
      float v1 = x0.x * mc.x + x0.y * mc.y + x0.z * mc.z + x0.w * mc.w       \
               + x1.x * md.x + x1.y * md.y + x1.z * md.z + x1.w * md.w       \
               + x8 * mr1[8];                                                \
      a1 = fmaf(v1, S##w12, a1);                                             \
      if (K == 0) {                                                          \
        const float* mr2 = &MeT[w][96];                                      \
        const float4 mg = *(const float4*)mr2;                               \
        const float4 mh = *(const float4*)(mr2 + 4);                         \
        float v2 = x0.x * mg.x + x0.y * mg.y + x0.z * mg.z + x0.w * mg.w     \
                 + x1.x * mh.x + x1.y * mh.y + x1.z * mh.z + x1.w * mh.w     \
                 + x8 * mr2[8];                                              \
        a2v = fmaf(v2, S##w12, a2v);                                         \
      }                                                                      \
    }                                                                        \
    __builtin_amdgcn_wave_barrier();                                         \
  }

__global__ __launch_bounds__(512, 6) void node_kernel(
    const float* __restrict__ x, const float* __restrict__ filt,
    const int* __restrict__ cnt, const int2* __restrict__ slots2,
    const float* __restrict__ w48, const float* __restrict__ CT,
    float* __restrict__ out) {
  __shared__ __align__(16) float xsl[8][16 * 12];
  __shared__ __align__(16) float MeT[8][9 * 12];
  __shared__ __align__(16) float red[8][64][3];
  const int t = threadIdx.x, w = t >> 6, l = t & 63;
  const int n = blockIdx.x;

  int deg = cnt[n];
  if (deg > 96) deg = 96;
  const int2* sl2 = slots2 + (size_t)n * 96;

  const int m = l & 15, K = l >> 4;
  const int wc0 = m * 3 + ((K == 0) ? 0 : 1);
  const int wc12 = m * 3 + 2;
  const int dd0 = l / 9, p0 = l % 9;
  const int dd1 = (l + 64) / 9, p1 = (l + 64) % 9;
  const int me0 = dd0 * 12 + p0;
  const int me1 = dd1 * 12 + p1;

  int wa0, wa1, wa2, wa3;
  {
    const int j0 = l * 4;
    wa0 = (j0 / 9) * 12 + (j0 % 9);
    wa1 = ((j0 + 1) / 9) * 12 + ((j0 + 1) % 9);
    wa2 = ((j0 + 2) / 9) * 12 + ((j0 + 2) % 9);
    wa3 = ((j0 + 3) / 9) * 12 + ((j0 + 3) % 9);
  }

  const float* c0p = CT + (dd0 * 9 + p0) * 12;
  const float4 C0a = *(const float4*)c0p;
  const float4 C0b = *(const float4*)(c0p + 4);
  const float  C0c = c0p[8];
  const float* c1p = CT + ((l < 17) ? (dd1 * 9 + p1) * 12 : 0);
  const float4 C1a = *(const float4*)c1p;
  const float4 C1b = *(const float4*)(c1p + 4);
  const float  C1c = c1p[8];

  float a0 = 0.f, a1 = 0.f, a2v = 0.f;

  float Af[9], Bf[9], Cf[9];
  float4 Ax, Bx, Cx;
  float Aw0, Aw12, Bw0, Bw12, Cw0, Cw12;

  int i = w;
  NLOAD(A, i);
  NLOAD(B, i + 8);
  while (true) {
    if (i >= deg) break;
    NLOAD(C, i + 16);
    NCOMPUTE(A);
    i += 8;
    if (i >= deg) break;
    NLOAD(A, i + 16);
    NCOMPUTE(B);
    i += 8;
    if (i >= deg) break;
    NLOAD(B, i + 16);
    NCOMPUTE(C);
    i += 8;
  }

  red[w][l][0] = a0;
  red[w][l][1] = a1;
  red[w][l][2] = a2v;
  __syncthreads();

  if (t < 144) {
    const int mm = t / 9, d = t % 9;
    int lane, slot;
    if (d < 4)      { lane = d * 16 + mm;       slot = 0; }
    else if (d < 8) { lane = (d - 4) * 16 + mm; slot = 1; }
    else            { lane = mm;                slot = 2; }
    float sum = 0.f;
#pragma unroll
    for (int ww = 0; ww < 8; ++ww) sum += red[ww][lane][slot];
    out[(size_t)n * 144 + t] = sum;
  }
}

// ---------------------------------------------------------------------------
extern "C" void kernel_launch(void* const* d_in, const int* in_sizes, int n_in,
                              void* d_out, int out_size, void* d_ws, size_t ws_size,
                              hipStream_t stream) {
  const float* x      = (const float*)d_in[0];
  const float* filt   = (const float*)d_in[1];
  const float* win    = (const float*)d_in[2];
  const int*   eidx   = (const int*)d_in[3];
  const float* Ux_re  = (const float*)d_in[4];
  const float* Ux_im  = (const float*)d_in[5];
  const float* Uf_re  = (const float*)d_in[6];
  const float* Uf_im  = (const float*)d_in[7];
  const float* Vo_re  = (const float*)d_in[8];
  const float* Vo_im  = (const float*)d_in[9];
  const float* W1     = (const float*)d_in[10];
  const float* W2     = (const float*)d_in[11];
  const float* W3     = (const float*)d_in[12];
  const float* a_w    = (const float*)d_in[13];
  const float* den    = (const float*)d_in[14];
  float* out = (float*)d_out;

  const int N = in_sizes[0] / 144;          // 10000
  const int E = in_sizes[3] / 2;            // 160000
  const int* dst = eidx;
  const int* src = eidx + E;

  char* wsb = (char*)d_ws;
  float* CT    = (float*)wsb;                                 // 8192 B region
  int*   cnt   = (int*)(wsb + 8192);                          // N ints
  int2*  slot2 = (int2*)(wsb + 8192 + 40960);                 // N*96 int2
  float* w48   = (float*)(wsb + 8192 + 40960 + (size_t)N * 96 * 8);

  const int nMlp = E / 128;                 // 1250
  const int nScat = (E + 255) / 256;        // 625

  hipMemsetAsync(cnt, 0, (size_t)N * sizeof(int), stream);
  prep_kernel<<<nMlp + nScat + 9, 256, 0, stream>>>(
      win, W1, W2, W3, a_w, den, w48,
      dst, src, E, cnt, slot2,
      Ux_re, Ux_im, Uf_re, Uf_im, Vo_re, Vo_im, CT, nMlp, nScat);
  node_kernel<<<N, 512, 0, stream>>>(x, filt, cnt, slot2, w48, CT, out);
}

// Round 7
// 113.981 us; speedup vs baseline: 2.5903x; 2.5903x over previous
//
#include <hip/hip_runtime.h>
#include <math.h>

#define PI9 (2.0f * 3.14159265358979323846f / 9.0f)

typedef float f32x4 __attribute__((ext_vector_type(4)));
typedef unsigned short us8 __attribute__((ext_vector_type(8)));
typedef __bf16 bf16x8 __attribute__((ext_vector_type(8)));

__device__ __forceinline__ float ssp_f(float x) {
  const float ax = fabsf(x);
  const float t = __expf(-ax);
  return fmaxf(x, 0.f) + __logf(1.f + t) - 0.69314718f;
}

__device__ __forceinline__ unsigned short f2bf(float f) {
  unsigned int u = __float_as_uint(f);
  unsigned int r = (u + 0x7FFFu + ((u >> 16) & 1u)) >> 16;
  return (unsigned short)r;
}

// ===========================================================================
// prep_kernel: blocks [0,nMlp) = MLP, [nMlp,nMlp+nScat) = scatter,
//              [nMlp+nScat, +9) = precompute_C.   Shared-memory union 32 KB.
// (unchanged from round 6 — verified fast & correct)
// ===========================================================================
__device__ void mlp_body(
    int mblk, unsigned char* smem, const float* __restrict__ win,
    const float* __restrict__ W1, const float* __restrict__ W2,
    const float* __restrict__ W3, const float* __restrict__ a_w,
    const float* __restrict__ den, float* __restrict__ w48) {
  float* W1s = (float*)smem;                              // 2048 B
  unsigned short* W2T = (unsigned short*)(smem + 2048);   // 8192 B
  unsigned short* W3T = (unsigned short*)(smem + 10240);  // 6144 B
  unsigned short* H1 = (unsigned short*)(smem + 16384);   // 8192 B
  unsigned short* H2 = (unsigned short*)(smem + 24576);   // 8192 B
  const int t = threadIdx.x;

  const float invden = 1.f / den[0];
  const float sc0 = a_w[0] * invden, sc1 = a_w[10] * invden, sc2 = a_w[22] * invden;
  const float rs8 = 0.35355339059327373f;

  if (t < 128) {
    float4 v = ((const float4*)W1)[t];
    v.x *= rs8; v.y *= rs8; v.z *= rs8; v.w *= rs8;
    ((float4*)W1s)[t] = v;
  }
  for (int i = t; i < 4096; i += 256) {
    const int k = i >> 6, j = i & 63;
    W2T[j * 64 + ((((k >> 3) ^ (j & 7)) << 3)) + (k & 7)] = f2bf(W2[i] * 0.125f);
  }
  for (int i = t; i < 3072; i += 256) {
    const int k = i / 48, j = i % 48;
    const int jm = j % 3;
    const float s = (jm == 0) ? sc0 : ((jm == 1) ? sc1 : sc2);
    W3T[j * 64 + ((((k >> 3) ^ (j & 7)) << 3)) + (k & 7)] = f2bf(W3[i] * 0.125f * s);
  }
  __syncthreads();

  const int w = t >> 6, l = t & 63;
  const int er = l & 15, g = l >> 4;
  unsigned short* h1p = H1 + w * 1024;
  unsigned short* h2p = H2 + w * 1024;

#pragma unroll 1
  for (int rep = 0; rep < 2; ++rep) {
    const int e = mblk * 128 + rep * 64 + w * 16 + er;

    float in8[8];
    {
      const float4 A = *(const float4*)(win + (size_t)e * 8);
      const float4 B = *(const float4*)(win + (size_t)e * 8 + 4);
      in8[0] = A.x; in8[1] = A.y; in8[2] = A.z; in8[3] = A.w;
      in8[4] = B.x; in8[5] = B.y; in8[6] = B.z; in8[7] = B.w;
    }
    float h[16];
#pragma unroll
    for (int c = 0; c < 16; ++c) h[c] = 0.f;
#pragma unroll
    for (int k = 0; k < 8; ++k) {
      const float* wr = &W1s[k * 64 + g * 16];
      const float4 w0 = *(const float4*)wr;
      const float4 w1 = *(const float4*)(wr + 4);
      const float4 w2 = *(const float4*)(wr + 8);
      const float4 w3 = *(const float4*)(wr + 12);
      const float ik = in8[k];
      h[0]  = fmaf(ik, w0.x, h[0]);  h[1]  = fmaf(ik, w0.y, h[1]);
      h[2]  = fmaf(ik, w0.z, h[2]);  h[3]  = fmaf(ik, w0.w, h[3]);
      h[4]  = fmaf(ik, w1.x, h[4]);  h[5]  = fmaf(ik, w1.y, h[5]);
      h[6]  = fmaf(ik, w1.z, h[6]);  h[7]  = fmaf(ik, w1.w, h[7]);
      h[8]  = fmaf(ik, w2.x, h[8]);  h[9]  = fmaf(ik, w2.y, h[9]);
      h[10] = fmaf(ik, w2.z, h[10]); h[11] = fmaf(ik, w2.w, h[11]);
      h[12] = fmaf(ik, w3.x, h[12]); h[13] = fmaf(ik, w3.y, h[13]);
      h[14] = fmaf(ik, w3.z, h[14]); h[15] = fmaf(ik, w3.w, h[15]);
    }
    us8 pk0, pk1;
#pragma unroll
    for (int jj = 0; jj < 8; ++jj) pk0[jj] = f2bf(ssp_f(h[jj]));
#pragma unroll
    for (int jj = 0; jj < 8; ++jj) pk1[jj] = f2bf(ssp_f(h[8 + jj]));
    *(us8*)&h1p[er * 64 + (((2 * g) ^ (er & 7)) << 3)] = pk0;
    *(us8*)&h1p[er * 64 + (((2 * g + 1) ^ (er & 7)) << 3)] = pk1;
    __builtin_amdgcn_wave_barrier();

    const us8 a0 = *(const us8*)&h1p[er * 64 + ((g ^ (er & 7)) << 3)];
    const us8 a1 = *(const us8*)&h1p[er * 64 + (((g + 4) ^ (er & 7)) << 3)];
    float hh[16];
#pragma unroll
    for (int nt = 0; nt < 4; ++nt) {
      const int j = nt * 16 + er;
      const us8 b0 = *(const us8*)&W2T[j * 64 + ((g ^ (j & 7)) << 3)];
      const us8 b1 = *(const us8*)&W2T[j * 64 + (((g + 4) ^ (j & 7)) << 3)];
      f32x4 acc = {0.f, 0.f, 0.f, 0.f};
      acc = __builtin_amdgcn_mfma_f32_16x16x32_bf16(
          __builtin_bit_cast(bf16x8, a0), __builtin_bit_cast(bf16x8, b0), acc, 0, 0, 0);
      acc = __builtin_amdgcn_mfma_f32_16x16x32_bf16(
          __builtin_bit_cast(bf16x8, a1), __builtin_bit_cast(bf16x8, b1), acc, 0, 0, 0);
#pragma unroll
      for (int r = 0; r < 4; ++r) hh[nt * 4 + r] = ssp_f(acc[r]);
    }
#pragma unroll
    for (int nt = 0; nt < 4; ++nt)
#pragma unroll
      for (int r = 0; r < 4; ++r) {
        const int e2 = g * 4 + r;
        const int k2 = nt * 16 + er;
        h2p[e2 * 64 + ((((k2 >> 3) ^ (e2 & 7)) << 3)) + (k2 & 7)] = f2bf(hh[nt * 4 + r]);
      }
    __builtin_amdgcn_wave_barrier();

    const us8 c0 = *(const us8*)&h2p[er * 64 + ((g ^ (er & 7)) << 3)];
    const us8 c1 = *(const us8*)&h2p[er * 64 + (((g + 4) ^ (er & 7)) << 3)];
    const int ebase = mblk * 128 + rep * 64 + w * 16 + g * 4;
#pragma unroll
    for (int nt = 0; nt < 3; ++nt) {
      const int o = nt * 16 + er;
      const us8 b0 = *(const us8*)&W3T[o * 64 + ((g ^ (o & 7)) << 3)];
      const us8 b1 = *(const us8*)&W3T[o * 64 + (((g + 4) ^ (o & 7)) << 3)];
      f32x4 acc = {0.f, 0.f, 0.f, 0.f};
      acc = __builtin_amdgcn_mfma_f32_16x16x32_bf16(
          __builtin_bit_cast(bf16x8, c0), __builtin_bit_cast(bf16x8, b0), acc, 0, 0, 0);
      acc = __builtin_amdgcn_mfma_f32_16x16x32_bf16(
          __builtin_bit_cast(bf16x8, c1), __builtin_bit_cast(bf16x8, b1), acc, 0, 0, 0);
#pragma unroll
      for (int r = 0; r < 4; ++r)
        w48[(size_t)(ebase + r) * 48 + o] = acc[r];
    }
    __builtin_amdgcn_wave_barrier();
  }
}

__device__ void precompute_body(
    int d, unsigned char* smem,
    const float* __restrict__ Ux_re, const float* __restrict__ Ux_im,
    const float* __restrict__ Uf_re, const float* __restrict__ Uf_im,
    const float* __restrict__ Vo_re, const float* __restrict__ Vo_im,
    float* __restrict__ CT) {
  float* G = (float*)smem;                // 2*729 floats
  float* TL = (float*)(smem + 5840);
  float* cs9 = (float*)(smem + 8768);
  float* sn9 = (float*)(smem + 8816);
  const int t0 = threadIdx.x;

  if (t0 < 9) {
    float s, c;
    __sincosf(PI9 * (float)t0, &s, &c);
    cs9[t0] = c; sn9[t0] = s;
  }
  __syncthreads();

  for (int t = t0; t < 1458; t += 256) {
    const int which = t / 729, idx = t % 729;
    const int p = idx / 81, ab = idx % 81, a = ab / 9, b = ab % 9;
    const float* Ure = which ? Uf_re : Ux_re;
    const float* Uim = which ? Uf_im : Ux_im;
    float g = 0.f;
#pragma unroll
    for (int v = 0; v < 3; ++v) {
      const int uc = v + 2;
      float hre = 0.f, him = 0.f;
#pragma unroll
      for (int ui = 0; ui < 5; ++ui) {
        const int u = (ui + 7) % 9;
        const float re = Ure[p * 25 + ui * 5 + uc];
        const float im = Uim[p * 25 + ui * 5 + uc];
        const int k = (u * a) % 9;
        const float c = cs9[k], s = sn9[k];
        hre += re * c - im * s;
        him += re * s + im * c;
      }
      hre *= (1.f / 9.f); him *= (1.f / 9.f);
      if (v == 0) {
        g += hre;
      } else {
        const int k = (v * b) % 9;
        g += 2.f * (hre * cs9[k] - him * sn9[k]);
      }
    }
    G[which * 729 + p * 81 + ab] = g * (1.f / 9.f);
  }
  __syncthreads();

  for (int t = t0; t < 729; t += 256) {
    const int ab = t / 9, dd = t % 9, a = ab / 9, b = ab % 9;
    float acc = 0.f;
    for (int u = 0; u < 9; ++u)
      for (int v = 0; v < 5; ++v) {
        const int k = (u * a + v * b) % 9;
        acc += Vo_re[u * 45 + v * 9 + dd] * cs9[k]
             + Vo_im[u * 45 + v * 9 + dd] * sn9[k];
      }
    TL[ab * 9 + dd] = acc;
  }
  __syncthreads();

  if (t0 < 108) {
    const int p = t0 / 12, q = t0 % 12;
    float acc = 0.f;
    if (q < 9) {
      for (int ab = 0; ab < 81; ++ab)
        acc += G[p * 81 + ab] * G[729 + q * 81 + ab] * TL[ab * 9 + d];
    }
    CT[(d * 9 + p) * 12 + q] = acc;
  }
}

__global__ __launch_bounds__(256) void prep_kernel(
    const float* __restrict__ win, const float* __restrict__ W1,
    const float* __restrict__ W2, const float* __restrict__ W3,
    const float* __restrict__ a_w, const float* __restrict__ den,
    float* __restrict__ w48,
    const int* __restrict__ dst, const int* __restrict__ src, int E,
    int* __restrict__ cnt, int2* __restrict__ slots2,
    const float* __restrict__ Ux_re, const float* __restrict__ Ux_im,
    const float* __restrict__ Uf_re, const float* __restrict__ Uf_im,
    const float* __restrict__ Vo_re, const float* __restrict__ Vo_im,
    float* __restrict__ CT, int nMlp, int nScat) {
  __shared__ __align__(16) unsigned char smem[32768];
  const int bid = blockIdx.x;
  if (bid < nMlp) {
    mlp_body(bid, smem, win, W1, W2, W3, a_w, den, w48);
  } else if (bid < nMlp + nScat) {
    const int e = (bid - nMlp) * 256 + threadIdx.x;
    if (e < E) {
      const int d = dst[e];
      const int pos = atomicAdd(&cnt[d], 1);
      if (pos < 96) slots2[(size_t)d * 96 + pos] = make_int2(e, src[e]);
    }
  } else {
    precompute_body(bid - nMlp - nScat, smem, Ux_re, Ux_im, Uf_re, Uf_im,
                    Vo_re, Vo_im, CT);
  }
}

// ===========================================================================
// Node kernel v6: WAVE-PER-NODE.  4 independent waves/block, no __syncthreads,
// no cross-wave reduction.  2-state (1-deep) edge prefetch, packed (e,src)
// slots, C rows in VGPRs, padded per-wave LDS slabs, coalesced output.
// ===========================================================================
#define NLOADV(Fv, Xv, Wv0, Wv12, idx)                                       \
  {                                                                          \
    const int2 es_ = sl2[(idx)];                                             \
    const int e_ = __builtin_amdgcn_readfirstlane(es_.x);                    \
    const int s_ = __builtin_amdgcn_readfirstlane(es_.y);                    \
    _Pragma("unroll")                                                        \
    for (int q_ = 0; q_ < 9; ++q_) Fv[q_] = filt[(size_t)e_ * 9 + q_];       \
    if (l < 36) Xv = *(const float4*)(x + (size_t)s_ * 144 + l * 4);         \
    Wv0 = w48[(size_t)e_ * 48 + wc0];                                        \
    Wv12 = w48[(size_t)e_ * 48 + wc12];                                      \
  }

#define NCOMPUTEV(Fv, Xv, Wv0, Wv12)                                         \
  {                                                                          \
    if (l < 36) {                                                            \
      xsl[w][wa0] = Xv.x; xsl[w][wa1] = Xv.y;                                \
      xsl[w][wa2] = Xv.z; xsl[w][wa3] = Xv.w;                                \
    }                                                                        \
    {                                                                        \
      float me = Fv[0] * C0a.x;                                              \
      me = fmaf(Fv[1], C0a.y, me); me = fmaf(Fv[2], C0a.z, me);              \
      me = fmaf(Fv[3], C0a.w, me); me = fmaf(Fv[4], C0b.x, me);              \
      me = fmaf(Fv[5], C0b.y, me); me = fmaf(Fv[6], C0b.z, me);              \
      me = fmaf(Fv[7], C0b.w, me); me = fmaf(Fv[8], C0c, me);                \
      MeT[w][me0] = me;                                                      \
    }                                                                        \
    if (l < 17) {                                                            \
      float me = Fv[0] * C1a.x;                                              \
      me = fmaf(Fv[1], C1a.y, me); me = fmaf(Fv[2], C1a.z, me);              \
      me = fmaf(Fv[3], C1a.w, me); me = fmaf(Fv[4], C1b.x, me);              \
      me = fmaf(Fv[5], C1b.y, me); me = fmaf(Fv[6], C1b.z, me);              \
      me = fmaf(Fv[7], C1b.w, me); me = fmaf(Fv[8], C1c, me);                \
      MeT[w][me1] = me;                                                      \
    }                                                                        \
    __builtin_amdgcn_wave_barrier();                                         \
    {                                                                        \
      const float* xr = &xsl[w][m * 12];                                     \
      const float4 x0 = *(const float4*)xr;                                  \
      const float4 x1 = *(const float4*)(xr + 4);                            \
      const float x8 = xr[8];                                                \
      const float* mr0 = &MeT[w][K * 12];                                    \
      const float4 ma = *(const float4*)mr0;                                 \
      const float4 mb = *(const float4*)(mr0 + 4);                           \
      float v = x0.x * ma.x + x0.y * ma.y + x0.z * ma.z + x0.w * ma.w        \
              + x1.x * mb.x + x1.y * mb.y + x1.z * mb.z + x1.w * mb.w        \
              + x8 * mr0[8];                                                 \
      a0 = fmaf(v, Wv0, a0);                                                 \
      const float* mr1 = &MeT[w][(K + 4) * 12];                              \
      const float4 mc = *(const float4*)mr1;                                 \
      const float4 md = *(const float4*)(mr1 + 4);                           \
      float v1 = x0.x * mc.x + x0.y * mc.y + x0.z * mc.z + x0.w * mc.w       \
               + x1.x * md.x + x1.y * md.y + x1.z * md.z + x1.w * md.w       \
               + x8 * mr1[8];                                                \
      a1 = fmaf(v1, Wv12, a1);                                               \
      if (K == 0) {                                                          \
        const float* mr2 = &MeT[w][96];                                      \
        const float4 mg = *(const float4*)mr2;                               \
        const float4 mh = *(const float4*)(mr2 + 4);                         \
        float v2 = x0.x * mg.x + x0.y * mg.y + x0.z * mg.z + x0.w * mg.w     \
                 + x1.x * mh.x + x1.y * mh.y + x1.z * mh.z + x1.w * mh.w     \
                 + x8 * mr2[8];                                              \
        a2v = fmaf(v2, Wv12, a2v);                                           \
      }                                                                      \
    }                                                                        \
    __builtin_amdgcn_wave_barrier();                                         \
  }

__global__ __launch_bounds__(256) void node_kernel(
    const float* __restrict__ x, const float* __restrict__ filt,
    const int* __restrict__ cnt, const int2* __restrict__ slots2,
    const float* __restrict__ w48, const float* __restrict__ CT,
    float* __restrict__ out, int N, int totWaves) {
  __shared__ __align__(16) float xsl[4][16 * 12];
  __shared__ __align__(16) float MeT[4][9 * 12];
  __shared__ __align__(16) float osl[4][144];
  const int t = threadIdx.x, w = t >> 6, l = t & 63;

  const int m = l & 15, K = l >> 4;
  const int wc0 = m * 3 + ((K == 0) ? 0 : 1);
  const int wc12 = m * 3 + 2;
  const int dd0 = l / 9, p0 = l % 9;
  const int dd1 = (l + 64) / 9, p1 = (l + 64) % 9;
  const int me0 = dd0 * 12 + p0;
  const int me1 = dd1 * 12 + p1;

  int wa0, wa1, wa2, wa3;
  {
    const int j0 = l * 4;
    wa0 = (j0 / 9) * 12 + (j0 % 9);
    wa1 = ((j0 + 1) / 9) * 12 + ((j0 + 1) % 9);
    wa2 = ((j0 + 2) / 9) * 12 + ((j0 + 2) % 9);
    wa3 = ((j0 + 3) / 9) * 12 + ((j0 + 3) % 9);
  }

  const float* c0p = CT + (dd0 * 9 + p0) * 12;
  const float4 C0a = *(const float4*)c0p;
  const float4 C0b = *(const float4*)(c0p + 4);
  const float  C0c = c0p[8];
  const float* c1p = CT + ((l < 17) ? (dd1 * 9 + p1) * 12 : 0);
  const float4 C1a = *(const float4*)c1p;
  const float4 C1b = *(const float4*)(c1p + 4);
  const float  C1c = c1p[8];

  const int waveId = blockIdx.x * 4 + w;

  for (int n = waveId; n < N; n += totWaves) {
    int deg = cnt[n];
    if (deg > 96) deg = 96;
    const int2* sl2 = slots2 + (size_t)n * 96;

    float a0 = 0.f, a1 = 0.f, a2v = 0.f;

    if (deg > 0) {
      float Af[9], Bf[9];
      float4 Ax = make_float4(0.f, 0.f, 0.f, 0.f);
      float4 Bx = make_float4(0.f, 0.f, 0.f, 0.f);
      float Aw0, Aw12, Bw0, Bw12;

      NLOADV(Af, Ax, Aw0, Aw12, 0);
      int i = 0;
      while (true) {
        if (i + 1 < deg) NLOADV(Bf, Bx, Bw0, Bw12, i + 1);
        NCOMPUTEV(Af, Ax, Aw0, Aw12);
        ++i;
        if (i >= deg) break;
        if (i + 1 < deg) NLOADV(Af, Ax, Aw0, Aw12, i + 1);
        NCOMPUTEV(Bf, Bx, Bw0, Bw12);
        ++i;
        if (i >= deg) break;
      }
    }

    // stage output in LDS, then coalesced float4 stores
    osl[w][m * 9 + K] = a0;
    osl[w][m * 9 + K + 4] = a1;
    if (K == 0) osl[w][m * 9 + 8] = a2v;
    __builtin_amdgcn_wave_barrier();
    if (l < 36)
      *(float4*)(out + (size_t)n * 144 + l * 4) = *(const float4*)&osl[w][l * 4];
    __builtin_amdgcn_wave_barrier();
  }
}

// ---------------------------------------------------------------------------
extern "C" void kernel_launch(void* const* d_in, const int* in_sizes, int n_in,
                              void* d_out, int out_size, void* d_ws, size_t ws_size,
                              hipStream_t stream) {
  const float* x      = (const float*)d_in[0];
  const float* filt   = (const float*)d_in[1];
  const float* win    = (const float*)d_in[2];
  const int*   eidx   = (const int*)d_in[3];
  const float* Ux_re  = (const float*)d_in[4];
  const float* Ux_im  = (const float*)d_in[5];
  const float* Uf_re  = (const float*)d_in[6];
  const float* Uf_im  = (const float*)d_in[7];
  const float* Vo_re  = (const float*)d_in[8];
  const float* Vo_im  = (const float*)d_in[9];
  const float* W1     = (const float*)d_in[10];
  const float* W2     = (const float*)d_in[11];
  const float* W3     = (const float*)d_in[12];
  const float* a_w    = (const float*)d_in[13];
  const float* den    = (const float*)d_in[14];
  float* out = (float*)d_out;

  const int N = in_sizes[0] / 144;          // 10000
  const int E = in_sizes[3] / 2;            // 160000
  const int* dst = eidx;
  const int* src = eidx + E;

  char* wsb = (char*)d_ws;
  float* CT    = (float*)wsb;                                 // 8192 B region
  int*   cnt   = (int*)(wsb + 8192);                          // N ints
  int2*  slot2 = (int2*)(wsb + 8192 + 40960);                 // N*96 int2
  float* w48   = (float*)(wsb + 8192 + 40960 + (size_t)N * 96 * 8);

  const int nMlp = E / 128;                 // 1250
  const int nScat = (E + 255) / 256;        // 625

  hipMemsetAsync(cnt, 0, (size_t)N * sizeof(int), stream);
  prep_kernel<<<nMlp + nScat + 9, 256, 0, stream>>>(
      win, W1, W2, W3, a_w, den, w48,
      dst, src, E, cnt, slot2,
      Ux_re, Ux_im, Uf_re, Uf_im, Vo_re, Vo_im, CT, nMlp, nScat);

  const int nodeBlocks = (N + 3) / 4;       // 1 node per wave
  node_kernel<<<nodeBlocks, 256, 0, stream>>>(
      x, filt, cnt, slot2, w48, CT, out, N, nodeBlocks * 4);
}